// Round 8
// baseline (207.229 us; speedup 1.0000x reference)
//
#include <hip/hip_runtime.h>
#include <hip/hip_bf16.h>
#include <cstdint>
#include <cstddef>

#define DEVFN static __device__ __forceinline__

typedef __attribute__((ext_vector_type(8))) short bf16x8;
typedef __attribute__((ext_vector_type(4))) float f32x4;

static constexpr int kB = 8192;
static constexpr int kIN = 1024;
static constexpr int kH = 2048;

DEVFN unsigned short f32_to_bf16(float f) {
  union { float f; unsigned int u; } v; v.f = f;
  unsigned int x = v.u;
  x += 0x7fffu + ((x >> 16) & 1u);   // round-to-nearest-even
  return (unsigned short)(x >> 16);
}
DEVFN float bf16_to_f32(unsigned short u) {
  union { unsigned int u; float f; } v; v.u = (unsigned int)u << 16;
  return v.f;
}

// one fused cast pass: fp32 -> bf16 for all five panels (vec4 per thread)
__global__ void cast_all(const float* __restrict__ x, const float* __restrict__ Wx,
                         const float* __restrict__ Wh, const float* __restrict__ Uz,
                         const float* __restrict__ h,
                         unsigned short* __restrict__ xb, unsigned short* __restrict__ Wxb,
                         unsigned short* __restrict__ Wcat, unsigned short* __restrict__ Acat) {
  const long i = (long)blockIdx.x * blockDim.x + threadIdx.x;  // vec4 index
  const float* src; unsigned short* dst; int sh, stride, off; long li;
  if (i < 2097152L)      { li = i;            src = x;  dst = xb;   sh = 8; stride = 1024; off = 0; }
  else if (i < 2621440L) { li = i - 2097152L; src = Wx; dst = Wxb;  sh = 8; stride = 1024; off = 0; }
  else if (i < 3670016L) { li = i - 2621440L; src = Wh; dst = Wcat; sh = 9; stride = 4096; off = 0; }
  else if (i < 4718592L) { li = i - 3670016L; src = Uz; dst = Wcat; sh = 9; stride = 4096; off = 2048; }
  else                   { li = i - 4718592L; src = h;  dst = Acat; sh = 9; stride = 4096; off = 0; }
  float4 v = *(const float4*)(src + li * 4);
  const long row = li >> sh;
  const long col = (li & ((1L << sh) - 1)) * 4;
  unsigned short* d = dst + row * stride + off + col;
  ushort4 o;
  o.x = f32_to_bf16(v.x); o.y = f32_to_bf16(v.y);
  o.z = f32_to_bf16(v.z); o.w = f32_to_bf16(v.w);
  *(ushort4*)d = o;
}

typedef const __attribute__((address_space(1))) unsigned int* gptr_t;
typedef __attribute__((address_space(3))) unsigned int* lptr_t;
DEVFN void gload16(const unsigned short* g, unsigned short* l) {
  __builtin_amdgcn_global_load_lds((gptr_t)g, (lptr_t)l, 16, 0, 0);
}

DEVFN void bar() { __builtin_amdgcn_s_barrier(); }
#define VMC0() asm volatile("s_waitcnt vmcnt(0)" ::: "memory")
#define VMC2() asm volatile("s_waitcnt vmcnt(2)" ::: "memory")

// LDS geometry (reordered so ds_read = base + compile-time imm):
//   A regions: elems [0, 32768):      (buf*2 + half)*8192
//   B regions: elems [32768, 65536):  32768 + (buf*2 + half)*8192
//   each region = [128 rows][64 cols] bf16, 16 KiB.
// Swizzle (T2): element col stored at c ^ ((row&7)*8); since all row offsets
// are multiples of 8, row&7 == lr&7 (thread-constant) -> swizzle folds into
// the per-thread base pointer; every read is base + constant offset.
// global_load_lds writes LINEAR; global SOURCE col is pre-swizzled (rule 21).
//
// Balanced phase schedule (<=8 ds_read_b128 per phase; drain phases have 0):
//   quadrants per tile: Q00,Q01,Q10,Q11; tiles buf0,buf1 per pair.
//   reads : ph1 aHi(b0)+b23(b0) | ph2 post a<-A1(b0) | ph3 -- | ph4 b01(b1)+post aLo(b1)
//           ph5 aHi(b1)+b23(b1) | ph6 post a<-A1(b1) | ph7 -- | ph8 b01(b0')+post aLo(b0')
//   stages: ph1 A1h1 | ph3 B0'h0 | ph4 B0'h1 | ph5 A0'h0 | ph6 A0'h1
//           ph7 B1'h0 | ph8 B1'h1+A1'h0
//   drains: VMC2 at ph3 (completes buf1: prev ph7/ph8 + ph1)
//           VMC2 at ph7 (completes buf0': ph3..ph6)
//   All cross-wave hazards: each ds_read completes before the barrier after
//   its consuming MFMA; overwriting stages/reads are >=1 barrier later.

template<int BUF, int QM, int MI0, int MI1>
DEVFN void ldA(bf16x8 (&a)[4][2], const unsigned short* LA0, const unsigned short* LA1) {
#pragma unroll
  for (int mi = MI0; mi < MI1; ++mi) {
    a[mi][0] = *(const bf16x8*)(LA0 + BUF * 16384 + QM * 4096 + mi * 1024);
    a[mi][1] = *(const bf16x8*)(LA1 + BUF * 16384 + QM * 4096 + mi * 1024);
  }
}

template<int BUF, int QN>
DEVFN void ldB(bf16x8 (&b)[4][2], const unsigned short* LB0, const unsigned short* LB1) {
#pragma unroll
  for (int ni = 0; ni < 2; ++ni) {
    const int n = QN * 2 + ni;
    b[n][0] = *(const bf16x8*)(LB0 + BUF * 16384 + n * 1024);
    b[n][1] = *(const bf16x8*)(LB1 + BUF * 16384 + n * 1024);
  }
}

template<int QM, int QN>
DEVFN void mfmaQ(f32x4 (&acc)[8][4], bf16x8 (&a)[4][2], bf16x8 (&b)[4][2]) {
  __builtin_amdgcn_s_setprio(1);
#pragma unroll
  for (int mi = 0; mi < 4; ++mi)
#pragma unroll
    for (int ni = 0; ni < 2; ++ni)
#pragma unroll
      for (int kk = 0; kk < 2; ++kk)
        acc[QM * 4 + mi][QN * 2 + ni] = __builtin_amdgcn_mfma_f32_16x16x32_bf16(
            a[mi][kk], b[QN * 2 + ni][kk], acc[QM * 4 + mi][QN * 2 + ni], 0, 0, 0);
  __builtin_amdgcn_s_setprio(0);
}

// C = A (MxK) * W^T (W NxK); bias per col.
//  EPI==0: zOut = bf16(tanh(.))           (zOut = Acat z-half, ldhz stride)
//  EPI==1: u = sigmoid(.); out = u*h + (1-u)*z, h/z read bf16 from hzBuf
template<int EPI>
__global__ __launch_bounds__(512, 1)
void gemm256(const unsigned short* __restrict__ A,
             const unsigned short* __restrict__ W,
             const float* __restrict__ bias,
             int M, int K,
             unsigned short* __restrict__ zOut,
             const unsigned short* __restrict__ hzBuf, int ldhz,
             float* __restrict__ out, int ldo)
{
  __shared__ unsigned short lds[8][8192];
  unsigned short* L = &lds[0][0];

  const int nTM = M >> 8;
  const int bm = blockIdx.x % nTM, bn = blockIdx.x / nTM;
  const int rowBase = bm << 8, colBase = bn << 8;

  const int t = threadIdx.x;
  const int l = t & 63;
  const int w = t >> 6;
  const int lr = l & 15, lg = l >> 4;
  const int wm = w >> 2, wn = w & 3;

  // per-thread LDS read bases (swizzle folded in; kel1 = kel0 ^ 32)
  const int kel0 = (lg * 8) ^ ((lr & 7) * 8);
  const unsigned short* LA0 = L + wm * 8192 + lr * 64 + kel0;
  const unsigned short* LA1 = L + wm * 8192 + lr * 64 + (kel0 ^ 32);
  const unsigned short* LB0 = L + 32768 + (wn >> 1) * 8192 + (wn & 1) * 4096 + lr * 64 + kel0;
  const unsigned short* LB1 = L + 32768 + (wn >> 1) * 8192 + (wn & 1) * 4096 + lr * 64 + (kel0 ^ 32);

  // staging addresses: thread t covers lds elems [t*8, t*8+8) of each 8KB slab
  const int srow = t >> 3;                       // 0..63
  const int scol = (t & 7) * 8;                  // 0..56
  const int kcSrc = scol ^ ((srow & 7) * 8);     // inverse-swizzled source col
  const unsigned short* gA = A + (size_t)(rowBase + srow) * K + kcSrc;
  const unsigned short* gB = W + (size_t)(colBase + srow) * K + kcSrc;

  // STAGE(buf, op, half, kt): one 16KB half-tile, 2 x global_load_lds per thread
#define STAGE(BUF, OP, HALF, KT) do {                                          \
    const unsigned short* gs = ((OP) ? gB : gA)                                \
        + (size_t)((HALF) * 128) * K + (size_t)(KT) * 64;                      \
    unsigned short* ld = L + (OP) * 32768 + ((BUF) * 2 + (HALF)) * 8192        \
        + w * 512;                                                             \
    gload16(gs, ld);                                                           \
    gload16(gs + (size_t)64 * K, ld + 4096);                                   \
  } while (0)

  f32x4 acc[8][4] = {};
  bf16x8 a[4][2], b[4][2];

  // prologue: stage buf0=tile0, buf1=tile1 fully; drain; preload aLo + b01 (tile0)
  STAGE(0, 0, 0, 0); STAGE(0, 0, 1, 0); STAGE(0, 1, 0, 0); STAGE(0, 1, 1, 0);
  STAGE(1, 1, 0, 1); STAGE(1, 1, 1, 1); STAGE(1, 0, 0, 1); STAGE(1, 0, 1, 1);
  VMC0();
  bar();
  ldA<0, 0, 0, 2>(a, LA0, LA1);
  ldB<0, 0>(b, LB0, LB1);

  const int NP = K >> 7;   // pairs of BK=64 K-tiles
  for (int j = 0; j < NP; ++j) {
    const bool more = (j + 1 < NP);
    const int ktb1 = 2 * j + 1;                     // buf1-A h1 (this pair)
    const int kt0n = more ? 2 * j + 2 : 2 * j;      // buf0' (clamped: benign restage)
    const int kt1n = more ? 2 * j + 3 : 2 * j + 1;  // buf1' (clamped)

    // ph1: Q00-b0.  pre: aHi(A0,b0) + b23(b0).  stage A1h1.
    ldA<0, 0, 2, 4>(a, LA0, LA1);
    ldB<0, 1>(b, LB0, LB1);
    STAGE(1, 0, 1, ktb1);
    bar();
    mfmaQ<0, 0>(acc, a, b);
    bar();
    // ph2: Q01-b0.  post: a <- A1(b0) (WAR-safe after MFMA).
    bar();
    mfmaQ<0, 1>(acc, a, b);
    ldA<0, 1, 0, 4>(a, LA0, LA1);
    bar();
    // ph3: Q10-b0.  stage B0'h0.  VMC2 completes buf1 (prev ph7/ph8 + ph1).
    STAGE(0, 1, 0, kt0n);
    bar();
    mfmaQ<1, 0>(acc, a, b);
    VMC2();
    bar();
    // ph4: Q11-b0.  pre: b01 <- B(b1) (buf1 safe since ph3 drain+bar).
    //      stage B0'h1.  post: aLo <- A0(b1).
    ldB<1, 0>(b, LB0, LB1);
    STAGE(0, 1, 1, kt0n);
    bar();
    mfmaQ<1, 1>(acc, a, b);
    ldA<1, 0, 0, 2>(a, LA0, LA1);
    bar();
    // ph5: Q00-b1.  pre: aHi(A0,b1) + b23(b1).  stage A0'h0.
    ldA<1, 0, 2, 4>(a, LA0, LA1);
    ldB<1, 1>(b, LB0, LB1);
    STAGE(0, 0, 0, kt0n);
    bar();
    mfmaQ<0, 0>(acc, a, b);
    bar();
    // ph6: Q01-b1.  stage A0'h1.  post: a <- A1(b1).
    STAGE(0, 0, 1, kt0n);
    bar();
    mfmaQ<0, 1>(acc, a, b);
    ldA<1, 1, 0, 4>(a, LA0, LA1);
    bar();
    // ph7: Q10-b1.  stage B1'h0.  VMC2 completes buf0' (ph3..ph6).
    STAGE(1, 1, 0, kt1n);
    bar();
    mfmaQ<1, 0>(acc, a, b);
    VMC2();
    bar();
    // ph8: Q11-b1.  pre: b01 <- B(b0') (safe after ph7 drain+bar).
    //      stage B1'h1 + A1'h0.  post: aLo <- A0(b0').
    ldB<0, 0>(b, LB0, LB1);
    STAGE(1, 1, 1, kt1n);
    STAGE(1, 0, 0, kt1n);
    bar();
    mfmaQ<1, 1>(acc, a, b);
    ldA<0, 0, 0, 2>(a, LA0, LA1);
    bar();
  }
#undef STAGE

  // epilogue; C/D layout: col = lane&15, row = (lane>>4)*4 + reg  [HW-verified]
#pragma unroll
  for (int m = 0; m < 8; ++m) {
    const int r0 = rowBase + wm * 128 + m * 16 + lg * 4;
#pragma unroll
    for (int n = 0; n < 4; ++n) {
      const int c = colBase + wn * 64 + n * 16 + lr;
      const float bs = bias[c];
#pragma unroll
      for (int q = 0; q < 4; ++q) {
        const int r = r0 + q;
        const float pre = acc[m][n][q] + bs;
        if (EPI == 0) {
          zOut[(size_t)r * ldhz + c] = f32_to_bf16(tanhf(pre));
        } else {
          const float u = 1.0f / (1.0f + __expf(-pre));
          const float hv = bf16_to_f32(hzBuf[(size_t)r * ldhz + c]);
          const float zv = bf16_to_f32(hzBuf[(size_t)r * ldhz + 2048 + c]);
          out[(size_t)r * ldo + c] = u * hv + (1.0f - u) * zv;
        }
      }
    }
  }
}

extern "C" void kernel_launch(void* const* d_in, const int* in_sizes, int n_in,
                              void* d_out, int out_size, void* d_ws, size_t ws_size,
                              hipStream_t stream) {
  const float* h  = (const float*)d_in[0];   // (B,H)
  const float* x  = (const float*)d_in[1];   // (B,IN)
  const float* Wx = (const float*)d_in[2];   // (H,IN)
  const float* bx = (const float*)d_in[3];   // (H)
  const float* Wh = (const float*)d_in[4];   // (H,H)
  const float* Uz = (const float*)d_in[5];   // (H,H)
  const float* bu = (const float*)d_in[6];   // (H)
  float* out = (float*)d_out;

  unsigned short* ws   = (unsigned short*)d_ws;
  unsigned short* xb   = ws;                          // B*IN
  unsigned short* Wxb  = xb + (size_t)kB * kIN;       // H*IN
  unsigned short* Wcat = Wxb + (size_t)kH * kIN;      // H*2H  ([Wh|Uz])
  unsigned short* Acat = Wcat + (size_t)kH * 2 * kH;  // B*2H  ([h|z])

  // all fp32->bf16 casts in one pass: 8,912,896 vec4 units / 256 = 34816 blocks
  cast_all<<<34816, 256, 0, stream>>>(x, Wx, Wh, Uz, h, xb, Wxb, Wcat, Acat);

  const int grid = (kB / 256) * (kH / 256);  // 32 * 8 = 256 = 1 block/CU

  // GEMM1: z = tanh(x Wx^T + bx) -> bf16 into Acat[:, H:2H]
  gemm256<0><<<grid, 512, 0, stream>>>(
      xb, Wxb, bx, kB, kIN, Acat + kH, nullptr, 2 * kH, nullptr, 0);

  // GEMM2: u = sigmoid([h|z] [Wh|Uz]^T + bu); out = u*h + (1-u)*z (h,z bf16)
  gemm256<1><<<grid, 512, 0, stream>>>(
      Acat, Wcat, bu, kB, 2 * kH, nullptr, Acat, 2 * kH, out, kH);
}